// Round 1
// baseline (5487.108 us; speedup 1.0000x reference)
//
#include <hip/hip_runtime.h>

#define DT_C   0.1f
#define INV1P  0.9090909090909091f  /* 1/(1+DT) */

// ---------------- setup: degree / dinv / scan / CSR fill ----------------

__global__ __launch_bounds__(256) void k_deg(const int* __restrict__ dst,
                                             int* __restrict__ deg, int e) {
  int i = blockIdx.x * 256 + threadIdx.x;
  if (i < e) atomicAdd(&deg[dst[i]], 1);
}

__global__ __launch_bounds__(256) void k_dinv(const int* __restrict__ deg,
                                              float* __restrict__ dinv, int n) {
  int i = blockIdx.x * 256 + threadIdx.x;
  if (i < n) {
    float d = (float)deg[i];
    dinv[i] = rsqrtf(fmaxf(d, 1.0f));
  }
}

// single-block exclusive scan of deg -> rowptr (n up to ~1M fine)
__global__ __launch_bounds__(1024) void k_scan(const int* __restrict__ deg,
                                               int* __restrict__ rowptr, int n) {
  __shared__ int sums[1024];
  int t = threadIdx.x;
  int chunk = (n + 1023) >> 10;
  int b0 = t * chunk;
  int b1 = min(n, b0 + chunk);
  int s = 0;
  for (int i = b0; i < b1; ++i) s += deg[i];
  sums[t] = s;
  __syncthreads();
  for (int off = 1; off < 1024; off <<= 1) {
    int v = (t >= off) ? sums[t - off] : 0;
    __syncthreads();
    sums[t] += v;
    __syncthreads();
  }
  int excl = (t == 0) ? 0 : sums[t - 1];
  for (int i = b0; i < b1; ++i) { rowptr[i] = excl; excl += deg[i]; }
  if (t == 1023) rowptr[n] = excl;
}

__global__ __launch_bounds__(256) void k_fill(const int* __restrict__ src,
                                              const int* __restrict__ dst,
                                              const int* __restrict__ rowptr,
                                              int* __restrict__ cnt,
                                              const float* __restrict__ dinv,
                                              int* __restrict__ csr_src,
                                              float* __restrict__ csr_w, int e) {
  int i = blockIdx.x * 256 + threadIdx.x;
  if (i >= e) return;
  int s = src[i], d = dst[i];
  int pos = rowptr[d] + atomicAdd(&cnt[d], 1);
  csr_src[pos] = s;
  csr_w[pos]   = dinv[s] * dinv[d];
}

// ---------------- input GEMM: X0 = tanh(x @ Wlx + blx); init h, rhs ----------------
// block = 256 threads (4 waves), 16 rows per block, wave w does rows w*4..w*4+3

__global__ __launch_bounds__(256) void k_gemm_in(const float* __restrict__ x,
                                                 const float* __restrict__ Wlx,
                                                 const float* __restrict__ blx,
                                                 float* __restrict__ h,
                                                 float* __restrict__ rhs, int n) {
  __shared__ float ws[128 * 64];   // 32 KB
  __shared__ float xs[16 * 128];   // 8 KB
  int t = threadIdx.x;
  for (int i = t; i < 128 * 64; i += 256) ws[i] = Wlx[i];
  int base = blockIdx.x * 16;
  // cooperative load of 16 rows (2048 floats) as float4
  for (int v = t; v < 512; v += 256) {
    long idx = (long)base * 128 + v * 4;
    float4 val = {0.f, 0.f, 0.f, 0.f};
    if (idx < (long)n * 128) val = *(const float4*)(x + idx);
    *(float4*)(xs + v * 4) = val;
  }
  __syncthreads();
  int lane = t & 63;
  int wib  = t >> 6;
  float bl = blx[lane];
  for (int r = 0; r < 4; ++r) {
    int row = base + wib * 4 + r;
    if (row < n) {
      const float* xr = &xs[(wib * 4 + r) * 128];
      float acc = bl;
#pragma unroll 8
      for (int k = 0; k < 128; ++k) acc = fmaf(xr[k], ws[k * 64 + lane], acc);
      float X0 = tanhf(acc);
      int o = row * 128;
      // h = [X0, 1]; rhs_X = X0 (fX=0 since Y0=1); rhs_Y = 1 + DT*(X0-1)
      h[o + lane]        = X0;
      h[o + 64 + lane]   = 1.0f;
      rhs[o + lane]      = X0;
      rhs[o + 64 + lane] = 1.0f + DT_C * (X0 - 1.0f);
    }
  }
}

// ---------------- Jacobi step 1: Z1 = (rhs + DT*agg(rhs)) / (1+DT) ----------------
// one wave per node; lane holds channels {2*lane, 2*lane+1} (float2)

__global__ __launch_bounds__(256) void k_agg(const float* __restrict__ Zin,
                                             const float* __restrict__ rhsIn,
                                             float* __restrict__ Zout,
                                             const int* __restrict__ rowptr,
                                             const int* __restrict__ csr_src,
                                             const float* __restrict__ csr_w, int n) {
  int node = (blockIdx.x * 256 + threadIdx.x) >> 6;
  if (node >= n) return;
  int lane = threadIdx.x & 63;
  int beg = rowptr[node], end = rowptr[node + 1];
  const float2* Z2 = (const float2*)Zin;
  float ax = 0.f, ay = 0.f;
  for (int e = beg; e < end; ++e) {
    int s   = csr_src[e];
    float w = csr_w[e];
    float2 z = Z2[s * 64 + lane];
    ax = fmaf(w, z.x, ax);
    ay = fmaf(w, z.y, ay);
  }
  float2 r = ((const float2*)rhsIn)[node * 64 + lane];
  float2 o;
  o.x = (r.x + DT_C * ax) * INV1P;
  o.y = (r.y + DT_C * ay) * INV1P;
  ((float2*)Zout)[node * 64 + lane] = o;
}

// ---------------- Jacobi step 2 fused with h-update and next-layer rhs ----------------
// Z2 = (rhs + DT*agg(Z1))/(1+DT);  h' = (1-tau)h + tau*Z2;
// rhs' = [X + DT*X*(1-Y), Y + DT*Y*(X-1)]  via shfl_xor(32) X/Y pairing.

__global__ __launch_bounds__(256) void k_agg2(const float* __restrict__ Z1,
                                              float* __restrict__ rhs,
                                              float* __restrict__ h,
                                              const int* __restrict__ rowptr,
                                              const int* __restrict__ csr_src,
                                              const float* __restrict__ csr_w,
                                              const float* __restrict__ taus,
                                              int layer, int n) {
  int node = (blockIdx.x * 256 + threadIdx.x) >> 6;
  if (node >= n) return;
  int lane = threadIdx.x & 63;
  int beg = rowptr[node], end = rowptr[node + 1];
  const float2* Z2p = (const float2*)Z1;
  float ax = 0.f, ay = 0.f;
  for (int e = beg; e < end; ++e) {
    int s   = csr_src[e];
    float w = csr_w[e];
    float2 z = Z2p[s * 64 + lane];
    ax = fmaf(w, z.x, ax);
    ay = fmaf(w, z.y, ay);
  }
  float2 r = ((const float2*)rhs)[node * 64 + lane];
  float zx = (r.x + DT_C * ax) * INV1P;
  float zy = (r.y + DT_C * ay) * INV1P;
  float tv  = taus[layer];
  float tau = 1.0f / (1.0f + expf(-tv));
  float2 hv = ((const float2*)h)[node * 64 + lane];
  float hx = (1.0f - tau) * hv.x + tau * zx;
  float hy = (1.0f - tau) * hv.y + tau * zy;
  // partner lane^32 holds the matching Y (resp. X) channels
  float ox = __shfl_xor(hx, 32);
  float oy = __shfl_xor(hy, 32);
  float2 rn;
  if (lane < 32) {  // this lane holds X channels; (ox,oy) = Y
    rn.x = hx + DT_C * hx * (1.0f - ox);
    rn.y = hy + DT_C * hy * (1.0f - oy);
  } else {          // this lane holds Y channels; (ox,oy) = X
    rn.x = hx + DT_C * hx * (ox - 1.0f);
    rn.y = hy + DT_C * hy * (oy - 1.0f);
  }
  float2 hn = {hx, hy};
  ((float2*)h)[node * 64 + lane]   = hn;
  ((float2*)rhs)[node * 64 + lane] = rn;
}

// ---------------- readout GEMM: out = logit_scale * X @ Wro + bro ----------------

__global__ __launch_bounds__(256) void k_gemm_out(const float* __restrict__ h,
                                                  const float* __restrict__ Wro,
                                                  const float* __restrict__ bro,
                                                  const float* __restrict__ lscale,
                                                  float* __restrict__ out, int n) {
  __shared__ float ws[64 * 40];  // 10 KB
  __shared__ float xs[16 * 64];  // 4 KB
  int t = threadIdx.x;
  for (int i = t; i < 64 * 40; i += 256) ws[i] = Wro[i];
  int base = blockIdx.x * 16;
  // cooperative load of 16 rows' X-halves (1024 floats) as float4 (1 per thread)
  {
    int v = t;                 // v in [0,256)
    int rr = v >> 4;           // row within tile
    int row = base + rr;
    float4 val = {0.f, 0.f, 0.f, 0.f};
    if (row < n) val = *(const float4*)(h + (long)row * 128 + ((v * 4) & 63));
    *(float4*)(xs + v * 4) = val;
  }
  __syncthreads();
  float ls = *lscale;
  int lane = t & 63;
  int wib  = t >> 6;
  float bb = (lane < 40) ? bro[lane] : 0.f;
  for (int r = 0; r < 4; ++r) {
    int row = base + wib * 4 + r;
    if (row < n && lane < 40) {
      const float* xr = &xs[(wib * 4 + r) * 64];
      float acc = 0.f;
#pragma unroll
      for (int k = 0; k < 64; ++k) acc = fmaf(xr[k], ws[k * 40 + lane], acc);
      out[row * 40 + lane] = ls * acc + bb;
    }
  }
}

// ---------------- launch ----------------

extern "C" void kernel_launch(void* const* d_in, const int* in_sizes, int n_in,
                              void* d_out, int out_size, void* d_ws, size_t ws_size,
                              hipStream_t stream) {
  const float* x     = (const float*)d_in[0];
  const float* Wlx   = (const float*)d_in[1];
  const float* blx   = (const float*)d_in[2];
  // d_in[3] W_ly, d_in[4] b_ly: unused by the reference
  const float* taus  = (const float*)d_in[5];
  const float* lsc   = (const float*)d_in[6];
  const float* Wro   = (const float*)d_in[7];
  const float* bro   = (const float*)d_in[8];
  const int*   eidx  = (const int*)d_in[9];
  int n = in_sizes[0] / 128;
  int e = in_sizes[9] / 2;
  const int* srcp = eidx;
  const int* dstp = eidx + e;
  float* out = (float*)d_out;

  char* ws = (char*)d_ws;
  size_t off = 0;
  auto alloc = [&](size_t bytes) -> void* {
    void* p = ws + off;
    off += (bytes + 255) & ~(size_t)255;
    return p;
  };
  int*   deg     = (int*)  alloc((size_t)n * 4);
  float* dinv    = (float*)alloc((size_t)n * 4);
  int*   rowptr  = (int*)  alloc((size_t)(n + 1) * 4);
  int*   cnt     = (int*)  alloc((size_t)n * 4);
  int*   csr_src = (int*)  alloc((size_t)e * 4);
  float* csr_w   = (float*)alloc((size_t)e * 4);
  float* h       = (float*)alloc((size_t)n * 128 * 4);
  float* rhs     = (float*)alloc((size_t)n * 128 * 4);
  float* Z1      = (float*)alloc((size_t)n * 128 * 4);
  (void)ws_size; (void)n_in; (void)out_size;

  hipMemsetAsync(deg, 0, (size_t)n * 4, stream);
  hipMemsetAsync(cnt, 0, (size_t)n * 4, stream);

  int eb = (e + 255) / 256;
  int nb = (n + 255) / 256;
  k_deg<<<eb, 256, 0, stream>>>(dstp, deg, e);
  k_dinv<<<nb, 256, 0, stream>>>(deg, dinv, n);
  k_scan<<<1, 1024, 0, stream>>>(deg, rowptr, n);
  k_fill<<<eb, 256, 0, stream>>>(srcp, dstp, rowptr, cnt, dinv, csr_src, csr_w, e);

  int rb = (n + 15) / 16;
  k_gemm_in<<<rb, 256, 0, stream>>>(x, Wlx, blx, h, rhs, n);

  int ab = (n * 64 + 255) / 256;  // one wave per node
  for (int l = 0; l < 15; ++l) {
    k_agg <<<ab, 256, 0, stream>>>(rhs, rhs, Z1, rowptr, csr_src, csr_w, n);
    k_agg2<<<ab, 256, 0, stream>>>(Z1, rhs, h, rowptr, csr_src, csr_w, taus, l, n);
  }

  k_gemm_out<<<rb, 256, 0, stream>>>(h, Wro, bro, lsc, out, n);
}

// Round 2
// 4192.554 us; speedup vs baseline: 1.3088x; 1.3088x over previous
//
#include <hip/hip_runtime.h>

#define DT_C   0.1f
#define INV1P  0.9090909090909091f  /* 1/(1+DT) */

// ---------------- setup: degree / dinv / scan / CSR fill ----------------

__global__ __launch_bounds__(256) void k_deg(const int* __restrict__ dst,
                                             int* __restrict__ deg, int e) {
  int i = blockIdx.x * 256 + threadIdx.x;
  if (i < e) atomicAdd(&deg[dst[i]], 1);
}

__global__ __launch_bounds__(256) void k_dinv(const int* __restrict__ deg,
                                              float* __restrict__ dinv, int n) {
  int i = blockIdx.x * 256 + threadIdx.x;
  if (i < n) {
    float d = (float)deg[i];
    dinv[i] = rsqrtf(fmaxf(d, 1.0f));
  }
}

// single-block exclusive scan of deg -> rowptr
__global__ __launch_bounds__(1024) void k_scan(const int* __restrict__ deg,
                                               int* __restrict__ rowptr, int n) {
  __shared__ int sums[1024];
  int t = threadIdx.x;
  int chunk = (n + 1023) >> 10;
  int b0 = t * chunk;
  int b1 = min(n, b0 + chunk);
  int s = 0;
  for (int i = b0; i < b1; ++i) s += deg[i];
  sums[t] = s;
  __syncthreads();
  for (int off = 1; off < 1024; off <<= 1) {
    int v = (t >= off) ? sums[t - off] : 0;
    __syncthreads();
    sums[t] += v;
    __syncthreads();
  }
  int excl = (t == 0) ? 0 : sums[t - 1];
  for (int i = b0; i < b1; ++i) { rowptr[i] = excl; excl += deg[i]; }
  if (t == 1023) rowptr[n] = excl;
}

__global__ __launch_bounds__(256) void k_fill(const int* __restrict__ src,
                                              const int* __restrict__ dst,
                                              const int* __restrict__ rowptr,
                                              int* __restrict__ cnt,
                                              const float* __restrict__ dinv,
                                              int* __restrict__ csr_src,
                                              float* __restrict__ csr_w, int e) {
  int i = blockIdx.x * 256 + threadIdx.x;
  if (i >= e) return;
  int s = src[i], d = dst[i];
  int pos = rowptr[d] + atomicAdd(&cnt[d], 1);
  csr_src[pos] = s;
  csr_w[pos]   = dinv[s] * dinv[d];
}

// ---------------- input GEMM: X0 = tanh(x @ Wlx + blx); init h, rhs ----------------

__global__ __launch_bounds__(256) void k_gemm_in(const float* __restrict__ x,
                                                 const float* __restrict__ Wlx,
                                                 const float* __restrict__ blx,
                                                 float* __restrict__ h,
                                                 float* __restrict__ rhs, int n) {
  __shared__ float ws[128 * 64];   // 32 KB
  __shared__ float xs[16 * 128];   // 8 KB
  int t = threadIdx.x;
  for (int i = t; i < 128 * 64; i += 256) ws[i] = Wlx[i];
  int base = blockIdx.x * 16;
  for (int v = t; v < 512; v += 256) {
    long idx = (long)base * 128 + v * 4;
    float4 val = {0.f, 0.f, 0.f, 0.f};
    if (idx < (long)n * 128) val = *(const float4*)(x + idx);
    *(float4*)(xs + v * 4) = val;
  }
  __syncthreads();
  int lane = t & 63;
  int wib  = t >> 6;
  float bl = blx[lane];
  for (int r = 0; r < 4; ++r) {
    int row = base + wib * 4 + r;
    if (row < n) {
      const float* xr = &xs[(wib * 4 + r) * 128];
      float acc = bl;
#pragma unroll 8
      for (int k = 0; k < 128; ++k) acc = fmaf(xr[k], ws[k * 64 + lane], acc);
      float X0 = tanhf(acc);
      int o = row * 128;
      h[o + lane]        = X0;
      h[o + 64 + lane]   = 1.0f;
      rhs[o + lane]      = X0;
      rhs[o + 64 + lane] = 1.0f + DT_C * (X0 - 1.0f);
    }
  }
}

// ---------------- Jacobi step 1: Z1 = (rhs + DT*agg(rhs)) / (1+DT) ----------------
// one wave per node; lane holds channels {2*lane, 2*lane+1} (float2).
// Edge loop processed in batches of 8 with clamped tail -> 8 gathers in flight.

__global__ __launch_bounds__(256) void k_agg(const float* __restrict__ Zin,
                                             const float* __restrict__ rhsIn,
                                             float* __restrict__ Zout,
                                             const int* __restrict__ rowptr,
                                             const int* __restrict__ csr_src,
                                             const float* __restrict__ csr_w, int n) {
  int node = __builtin_amdgcn_readfirstlane((blockIdx.x * 256 + threadIdx.x) >> 6);
  if (node >= n) return;
  int lane = threadIdx.x & 63;
  int beg = __builtin_amdgcn_readfirstlane(rowptr[node]);
  int end = __builtin_amdgcn_readfirstlane(rowptr[node + 1]);
  const float2* __restrict__ Z2 = (const float2*)Zin;
  float2 r = ((const float2*)rhsIn)[(size_t)node * 64 + lane];

  float a0x = 0.f, a0y = 0.f, a1x = 0.f, a1y = 0.f;
  float a2x = 0.f, a2y = 0.f, a3x = 0.f, a3y = 0.f;
  int last = end - 1;
  for (int e0 = beg; e0 < end; e0 += 8) {
    int   s[8];
    float w[8];
    float2 z[8];
#pragma unroll
    for (int j = 0; j < 8; ++j) {
      int i  = e0 + j;
      int ic = (i < end) ? i : last;
      s[j] = csr_src[ic];
      w[j] = (i < end) ? csr_w[ic] : 0.f;
    }
#pragma unroll
    for (int j = 0; j < 8; ++j) z[j] = Z2[(size_t)s[j] * 64 + lane];
    a0x = fmaf(w[0], z[0].x, a0x); a0y = fmaf(w[0], z[0].y, a0y);
    a1x = fmaf(w[1], z[1].x, a1x); a1y = fmaf(w[1], z[1].y, a1y);
    a2x = fmaf(w[2], z[2].x, a2x); a2y = fmaf(w[2], z[2].y, a2y);
    a3x = fmaf(w[3], z[3].x, a3x); a3y = fmaf(w[3], z[3].y, a3y);
    a0x = fmaf(w[4], z[4].x, a0x); a0y = fmaf(w[4], z[4].y, a0y);
    a1x = fmaf(w[5], z[5].x, a1x); a1y = fmaf(w[5], z[5].y, a1y);
    a2x = fmaf(w[6], z[6].x, a2x); a2y = fmaf(w[6], z[6].y, a2y);
    a3x = fmaf(w[7], z[7].x, a3x); a3y = fmaf(w[7], z[7].y, a3y);
  }
  float ax = (a0x + a1x) + (a2x + a3x);
  float ay = (a0y + a1y) + (a2y + a3y);
  float2 o;
  o.x = (r.x + DT_C * ax) * INV1P;
  o.y = (r.y + DT_C * ay) * INV1P;
  ((float2*)Zout)[(size_t)node * 64 + lane] = o;
}

// ---------------- Jacobi step 2 fused with h-update and next-layer rhs ----------------

__global__ __launch_bounds__(256) void k_agg2(const float* __restrict__ Z1,
                                              float* __restrict__ rhs,
                                              float* __restrict__ h,
                                              const int* __restrict__ rowptr,
                                              const int* __restrict__ csr_src,
                                              const float* __restrict__ csr_w,
                                              const float* __restrict__ taus,
                                              int layer, int n) {
  int node = __builtin_amdgcn_readfirstlane((blockIdx.x * 256 + threadIdx.x) >> 6);
  if (node >= n) return;
  int lane = threadIdx.x & 63;
  int beg = __builtin_amdgcn_readfirstlane(rowptr[node]);
  int end = __builtin_amdgcn_readfirstlane(rowptr[node + 1]);
  const float2* __restrict__ Z2p = (const float2*)Z1;
  float2 r  = ((const float2*)rhs)[(size_t)node * 64 + lane];
  float2 hv = ((const float2*)h)[(size_t)node * 64 + lane];

  float a0x = 0.f, a0y = 0.f, a1x = 0.f, a1y = 0.f;
  float a2x = 0.f, a2y = 0.f, a3x = 0.f, a3y = 0.f;
  int last = end - 1;
  for (int e0 = beg; e0 < end; e0 += 8) {
    int   s[8];
    float w[8];
    float2 z[8];
#pragma unroll
    for (int j = 0; j < 8; ++j) {
      int i  = e0 + j;
      int ic = (i < end) ? i : last;
      s[j] = csr_src[ic];
      w[j] = (i < end) ? csr_w[ic] : 0.f;
    }
#pragma unroll
    for (int j = 0; j < 8; ++j) z[j] = Z2p[(size_t)s[j] * 64 + lane];
    a0x = fmaf(w[0], z[0].x, a0x); a0y = fmaf(w[0], z[0].y, a0y);
    a1x = fmaf(w[1], z[1].x, a1x); a1y = fmaf(w[1], z[1].y, a1y);
    a2x = fmaf(w[2], z[2].x, a2x); a2y = fmaf(w[2], z[2].y, a2y);
    a3x = fmaf(w[3], z[3].x, a3x); a3y = fmaf(w[3], z[3].y, a3y);
    a0x = fmaf(w[4], z[4].x, a0x); a0y = fmaf(w[4], z[4].y, a0y);
    a1x = fmaf(w[5], z[5].x, a1x); a1y = fmaf(w[5], z[5].y, a1y);
    a2x = fmaf(w[6], z[6].x, a2x); a2y = fmaf(w[6], z[6].y, a2y);
    a3x = fmaf(w[7], z[7].x, a3x); a3y = fmaf(w[7], z[7].y, a3y);
  }
  float ax = (a0x + a1x) + (a2x + a3x);
  float ay = (a0y + a1y) + (a2y + a3y);

  float zx = (r.x + DT_C * ax) * INV1P;
  float zy = (r.y + DT_C * ay) * INV1P;
  float tv  = taus[layer];
  float tau = 1.0f / (1.0f + expf(-tv));
  float hx = (1.0f - tau) * hv.x + tau * zx;
  float hy = (1.0f - tau) * hv.y + tau * zy;
  float ox = __shfl_xor(hx, 32);
  float oy = __shfl_xor(hy, 32);
  float2 rn;
  if (lane < 32) {
    rn.x = hx + DT_C * hx * (1.0f - ox);
    rn.y = hy + DT_C * hy * (1.0f - oy);
  } else {
    rn.x = hx + DT_C * hx * (ox - 1.0f);
    rn.y = hy + DT_C * hy * (oy - 1.0f);
  }
  float2 hn = {hx, hy};
  ((float2*)h)[(size_t)node * 64 + lane]   = hn;
  ((float2*)rhs)[(size_t)node * 64 + lane] = rn;
}

// ---------------- readout GEMM: out = logit_scale * X @ Wro + bro ----------------

__global__ __launch_bounds__(256) void k_gemm_out(const float* __restrict__ h,
                                                  const float* __restrict__ Wro,
                                                  const float* __restrict__ bro,
                                                  const float* __restrict__ lscale,
                                                  float* __restrict__ out, int n) {
  __shared__ float ws[64 * 40];
  __shared__ float xs[16 * 64];
  int t = threadIdx.x;
  for (int i = t; i < 64 * 40; i += 256) ws[i] = Wro[i];
  int base = blockIdx.x * 16;
  {
    int v = t;
    int rr = v >> 4;
    int row = base + rr;
    float4 val = {0.f, 0.f, 0.f, 0.f};
    if (row < n) val = *(const float4*)(h + (long)row * 128 + ((v * 4) & 63));
    *(float4*)(xs + v * 4) = val;
  }
  __syncthreads();
  float ls = *lscale;
  int lane = t & 63;
  int wib  = t >> 6;
  float bb = (lane < 40) ? bro[lane] : 0.f;
  for (int r = 0; r < 4; ++r) {
    int row = base + wib * 4 + r;
    if (row < n && lane < 40) {
      const float* xr = &xs[(wib * 4 + r) * 64];
      float acc = 0.f;
#pragma unroll
      for (int k = 0; k < 64; ++k) acc = fmaf(xr[k], ws[k * 40 + lane], acc);
      out[row * 40 + lane] = ls * acc + bb;
    }
  }
}

// ---------------- launch ----------------

extern "C" void kernel_launch(void* const* d_in, const int* in_sizes, int n_in,
                              void* d_out, int out_size, void* d_ws, size_t ws_size,
                              hipStream_t stream) {
  const float* x     = (const float*)d_in[0];
  const float* Wlx   = (const float*)d_in[1];
  const float* blx   = (const float*)d_in[2];
  const float* taus  = (const float*)d_in[5];
  const float* lsc   = (const float*)d_in[6];
  const float* Wro   = (const float*)d_in[7];
  const float* bro   = (const float*)d_in[8];
  const int*   eidx  = (const int*)d_in[9];
  int n = in_sizes[0] / 128;
  int e = in_sizes[9] / 2;
  const int* srcp = eidx;
  const int* dstp = eidx + e;
  float* out = (float*)d_out;

  char* ws = (char*)d_ws;
  size_t off = 0;
  auto alloc = [&](size_t bytes) -> void* {
    void* p = ws + off;
    off += (bytes + 255) & ~(size_t)255;
    return p;
  };
  int*   deg     = (int*)  alloc((size_t)n * 4);
  float* dinv    = (float*)alloc((size_t)n * 4);
  int*   rowptr  = (int*)  alloc((size_t)(n + 1) * 4);
  int*   cnt     = (int*)  alloc((size_t)n * 4);
  int*   csr_src = (int*)  alloc((size_t)e * 4);
  float* csr_w   = (float*)alloc((size_t)e * 4);
  float* h       = (float*)alloc((size_t)n * 128 * 4);
  float* rhs     = (float*)alloc((size_t)n * 128 * 4);
  float* Z1      = (float*)alloc((size_t)n * 128 * 4);
  (void)ws_size; (void)n_in; (void)out_size;

  hipMemsetAsync(deg, 0, (size_t)n * 4, stream);
  hipMemsetAsync(cnt, 0, (size_t)n * 4, stream);

  int eb = (e + 255) / 256;
  int nb = (n + 255) / 256;
  k_deg<<<eb, 256, 0, stream>>>(dstp, deg, e);
  k_dinv<<<nb, 256, 0, stream>>>(deg, dinv, n);
  k_scan<<<1, 1024, 0, stream>>>(deg, rowptr, n);
  k_fill<<<eb, 256, 0, stream>>>(srcp, dstp, rowptr, cnt, dinv, csr_src, csr_w, e);

  int rb = (n + 15) / 16;
  k_gemm_in<<<rb, 256, 0, stream>>>(x, Wlx, blx, h, rhs, n);

  int ab = (n * 64 + 255) / 256;  // one wave per node
  for (int l = 0; l < 15; ++l) {
    k_agg <<<ab, 256, 0, stream>>>(rhs, rhs, Z1, rowptr, csr_src, csr_w, n);
    k_agg2<<<ab, 256, 0, stream>>>(Z1, rhs, h, rowptr, csr_src, csr_w, taus, l, n);
  }

  k_gemm_out<<<rb, 256, 0, stream>>>(h, Wro, bro, lsc, out, n);
}

// Round 3
// 2527.387 us; speedup vs baseline: 2.1711x; 1.6588x over previous
//
#include <hip/hip_runtime.h>

#define DT_C   0.1f
#define INV1P  0.9090909090909091f  /* 1/(1+DT) */

// ---------------- bf16 pack/unpack (RNE) ----------------

__device__ __forceinline__ unsigned bf16rne(float f) {
  unsigned b = __float_as_uint(f);
  return (b + 0x7fffu + ((b >> 16) & 1u)) >> 16;
}
__device__ __forceinline__ unsigned packbf(float x, float y) {
  return bf16rne(x) | (bf16rne(y) << 16);
}

// ---------------- setup: degree / dinv / scan / CSR fill ----------------

__global__ __launch_bounds__(256) void k_deg(const int* __restrict__ dst,
                                             int* __restrict__ deg, int e) {
  int i = blockIdx.x * 256 + threadIdx.x;
  if (i < e) atomicAdd(&deg[dst[i]], 1);
}

__global__ __launch_bounds__(256) void k_dinv(const int* __restrict__ deg,
                                              float* __restrict__ dinv, int n) {
  int i = blockIdx.x * 256 + threadIdx.x;
  if (i < n) {
    float d = (float)deg[i];
    dinv[i] = rsqrtf(fmaxf(d, 1.0f));
  }
}

// multi-block scan, phase A: per-block local exclusive scan + block sums
__global__ __launch_bounds__(1024) void k_scanA(const int* __restrict__ deg,
                                                int* __restrict__ rowptr,
                                                int* __restrict__ bsum, int n) {
  __shared__ int sm[1024];
  int t = threadIdx.x;
  int i = blockIdx.x * 1024 + t;
  int v = (i < n) ? deg[i] : 0;
  sm[t] = v;
  __syncthreads();
  for (int off = 1; off < 1024; off <<= 1) {
    int u = (t >= off) ? sm[t - off] : 0;
    __syncthreads();
    sm[t] += u;
    __syncthreads();
  }
  if (i < n) rowptr[i] = sm[t] - v;  // local exclusive
  if (t == 1023) bsum[blockIdx.x] = sm[t];
}

// phase B: single-block exclusive scan of block sums (G <= 1024)
__global__ __launch_bounds__(1024) void k_scanB(int* __restrict__ bsum, int g) {
  __shared__ int sm[1024];
  int t = threadIdx.x;
  int v = (t < g) ? bsum[t] : 0;
  sm[t] = v;
  __syncthreads();
  for (int off = 1; off < 1024; off <<= 1) {
    int u = (t >= off) ? sm[t - off] : 0;
    __syncthreads();
    sm[t] += u;
    __syncthreads();
  }
  if (t < g) bsum[t] = sm[t] - v;  // exclusive
}

// phase C: add block offsets; write rowptr[n]
__global__ __launch_bounds__(1024) void k_scanC(int* __restrict__ rowptr,
                                                const int* __restrict__ bsum,
                                                int n, int etot) {
  int i = blockIdx.x * 1024 + threadIdx.x;
  if (i < n) rowptr[i] += bsum[blockIdx.x];
  if (i == 0) rowptr[n] = etot;
}

__global__ __launch_bounds__(256) void k_fill(const int* __restrict__ src,
                                              const int* __restrict__ dst,
                                              const int* __restrict__ rowptr,
                                              int* __restrict__ cnt,
                                              const float* __restrict__ dinv,
                                              int* __restrict__ csr_src,
                                              float* __restrict__ csr_w, int e) {
  int i = blockIdx.x * 256 + threadIdx.x;
  if (i >= e) return;
  int s = src[i], d = dst[i];
  int pos = rowptr[d] + atomicAdd(&cnt[d], 1);
  csr_src[pos] = s;
  csr_w[pos]   = dinv[s] * dinv[d];
}

// ---------------- input GEMM: X0 = tanh(x @ Wlx + blx); init h, rhs, rhs_b ----------------

__global__ __launch_bounds__(256) void k_gemm_in(const float* __restrict__ x,
                                                 const float* __restrict__ Wlx,
                                                 const float* __restrict__ blx,
                                                 float* __restrict__ h,
                                                 float* __restrict__ rhs,
                                                 unsigned* __restrict__ rhs_b, int n) {
  __shared__ float ws[128 * 64];   // 32 KB
  __shared__ float xs[16 * 128];   // 8 KB
  int t = threadIdx.x;
  for (int i = t; i < 128 * 64; i += 256) ws[i] = Wlx[i];
  int base = blockIdx.x * 16;
  for (int v = t; v < 512; v += 256) {
    long idx = (long)base * 128 + v * 4;
    float4 val = {0.f, 0.f, 0.f, 0.f};
    if (idx < (long)n * 128) val = *(const float4*)(x + idx);
    *(float4*)(xs + v * 4) = val;
  }
  __syncthreads();
  int lane = t & 63;
  int wib  = t >> 6;
  float bl = blx[lane];
  for (int r = 0; r < 4; ++r) {
    int row = base + wib * 4 + r;
    if (row < n) {
      const float* xr = &xs[(wib * 4 + r) * 128];
      float acc = bl;
#pragma unroll 8
      for (int k = 0; k < 128; ++k) acc = fmaf(xr[k], ws[k * 64 + lane], acc);
      float X0 = tanhf(acc);
      int o = row * 128;
      h[o + lane]        = X0;
      h[o + 64 + lane]   = 1.0f;
      rhs[o + lane]      = X0;
      rhs[o + 64 + lane] = 1.0f + DT_C * (X0 - 1.0f);
      // bf16 copy of rhs, channel-pair layout: word w = channels (2w, 2w+1)
      float a = __shfl(X0, (2 * lane) & 63);
      float b = __shfl(X0, (2 * lane + 1) & 63);
      float px, py;
      if (lane < 32) { px = a; py = b; }
      else { px = 1.f + DT_C * (a - 1.f); py = 1.f + DT_C * (b - 1.f); }
      rhs_b[(size_t)row * 64 + lane] = packbf(px, py);
    }
  }
}

// ---------------- Jacobi step 1: Z1b = bf16((rhs + DT*agg(rhs_b)) / (1+DT)) ----------------
// one wave per node; lane holds channel pair {2*lane, 2*lane+1}; 16 gathers in flight.

__global__ __launch_bounds__(256) void k_agg(const unsigned* __restrict__ Zb,
                                             const float* __restrict__ rhsIn,
                                             unsigned* __restrict__ Z1b,
                                             const int* __restrict__ rowptr,
                                             const int* __restrict__ csr_src,
                                             const float* __restrict__ csr_w, int n) {
  int node = __builtin_amdgcn_readfirstlane((blockIdx.x * 256 + threadIdx.x) >> 6);
  if (node >= n) return;
  int lane = threadIdx.x & 63;
  int beg = __builtin_amdgcn_readfirstlane(rowptr[node]);
  int end = __builtin_amdgcn_readfirstlane(rowptr[node + 1]);
  float2 r = ((const float2*)rhsIn)[(size_t)node * 64 + lane];

  float accx[4] = {0.f, 0.f, 0.f, 0.f};
  float accy[4] = {0.f, 0.f, 0.f, 0.f};
  int last = end - 1;
  for (int e0 = beg; e0 < end; e0 += 16) {
    int s[16]; float w[16]; unsigned u[16];
#pragma unroll
    for (int j = 0; j < 16; ++j) {
      int i  = e0 + j;
      int ic = (i < end) ? i : last;
      s[j] = csr_src[ic];
      w[j] = (i < end) ? csr_w[ic] : 0.f;
    }
#pragma unroll
    for (int j = 0; j < 16; ++j) u[j] = Zb[(size_t)s[j] * 64 + lane];
#pragma unroll
    for (int j = 0; j < 16; ++j) {
      float zx = __uint_as_float(u[j] << 16);
      float zy = __uint_as_float(u[j] & 0xffff0000u);
      accx[j & 3] = fmaf(w[j], zx, accx[j & 3]);
      accy[j & 3] = fmaf(w[j], zy, accy[j & 3]);
    }
  }
  float ax = (accx[0] + accx[1]) + (accx[2] + accx[3]);
  float ay = (accy[0] + accy[1]) + (accy[2] + accy[3]);
  float ox = (r.x + DT_C * ax) * INV1P;
  float oy = (r.y + DT_C * ay) * INV1P;
  Z1b[(size_t)node * 64 + lane] = packbf(ox, oy);
}

// ---------------- Jacobi step 2 fused with h-update and next-layer rhs ----------------

__global__ __launch_bounds__(256) void k_agg2(const unsigned* __restrict__ Z1b,
                                              float* __restrict__ rhs,
                                              unsigned* __restrict__ rhs_b,
                                              float* __restrict__ h,
                                              const int* __restrict__ rowptr,
                                              const int* __restrict__ csr_src,
                                              const float* __restrict__ csr_w,
                                              const float* __restrict__ taus,
                                              int layer, int n) {
  int node = __builtin_amdgcn_readfirstlane((blockIdx.x * 256 + threadIdx.x) >> 6);
  if (node >= n) return;
  int lane = threadIdx.x & 63;
  int beg = __builtin_amdgcn_readfirstlane(rowptr[node]);
  int end = __builtin_amdgcn_readfirstlane(rowptr[node + 1]);
  float2 r  = ((const float2*)rhs)[(size_t)node * 64 + lane];
  float2 hv = ((const float2*)h)[(size_t)node * 64 + lane];

  float accx[4] = {0.f, 0.f, 0.f, 0.f};
  float accy[4] = {0.f, 0.f, 0.f, 0.f};
  int last = end - 1;
  for (int e0 = beg; e0 < end; e0 += 16) {
    int s[16]; float w[16]; unsigned u[16];
#pragma unroll
    for (int j = 0; j < 16; ++j) {
      int i  = e0 + j;
      int ic = (i < end) ? i : last;
      s[j] = csr_src[ic];
      w[j] = (i < end) ? csr_w[ic] : 0.f;
    }
#pragma unroll
    for (int j = 0; j < 16; ++j) u[j] = Z1b[(size_t)s[j] * 64 + lane];
#pragma unroll
    for (int j = 0; j < 16; ++j) {
      float zx = __uint_as_float(u[j] << 16);
      float zy = __uint_as_float(u[j] & 0xffff0000u);
      accx[j & 3] = fmaf(w[j], zx, accx[j & 3]);
      accy[j & 3] = fmaf(w[j], zy, accy[j & 3]);
    }
  }
  float ax = (accx[0] + accx[1]) + (accx[2] + accx[3]);
  float ay = (accy[0] + accy[1]) + (accy[2] + accy[3]);

  float zx = (r.x + DT_C * ax) * INV1P;
  float zy = (r.y + DT_C * ay) * INV1P;
  float tv  = taus[layer];
  float tau = 1.0f / (1.0f + expf(-tv));
  float hx = (1.0f - tau) * hv.x + tau * zx;
  float hy = (1.0f - tau) * hv.y + tau * zy;
  float ox = __shfl_xor(hx, 32);
  float oy = __shfl_xor(hy, 32);
  float2 rn;
  if (lane < 32) {  // channels 2l,2l+1 are X; partner holds matching Y
    rn.x = hx + DT_C * hx * (1.0f - ox);
    rn.y = hy + DT_C * hy * (1.0f - oy);
  } else {          // Y channels; partner holds X
    rn.x = hx + DT_C * hx * (ox - 1.0f);
    rn.y = hy + DT_C * hy * (oy - 1.0f);
  }
  float2 hn = {hx, hy};
  ((float2*)h)[(size_t)node * 64 + lane]   = hn;
  ((float2*)rhs)[(size_t)node * 64 + lane] = rn;
  rhs_b[(size_t)node * 64 + lane] = packbf(rn.x, rn.y);
}

// ---------------- readout GEMM: out = logit_scale * X @ Wro + bro ----------------

__global__ __launch_bounds__(256) void k_gemm_out(const float* __restrict__ h,
                                                  const float* __restrict__ Wro,
                                                  const float* __restrict__ bro,
                                                  const float* __restrict__ lscale,
                                                  float* __restrict__ out, int n) {
  __shared__ float ws[64 * 40];
  __shared__ float xs[16 * 64];
  int t = threadIdx.x;
  for (int i = t; i < 64 * 40; i += 256) ws[i] = Wro[i];
  int base = blockIdx.x * 16;
  {
    int v = t;
    int rr = v >> 4;
    int row = base + rr;
    float4 val = {0.f, 0.f, 0.f, 0.f};
    if (row < n) val = *(const float4*)(h + (long)row * 128 + ((v * 4) & 63));
    *(float4*)(xs + v * 4) = val;
  }
  __syncthreads();
  float ls = *lscale;
  int lane = t & 63;
  int wib  = t >> 6;
  float bb = (lane < 40) ? bro[lane] : 0.f;
  for (int r = 0; r < 4; ++r) {
    int row = base + wib * 4 + r;
    if (row < n && lane < 40) {
      const float* xr = &xs[(wib * 4 + r) * 64];
      float acc = 0.f;
#pragma unroll
      for (int k = 0; k < 64; ++k) acc = fmaf(xr[k], ws[k * 40 + lane], acc);
      out[row * 40 + lane] = ls * acc + bb;
    }
  }
}

// ---------------- launch ----------------

extern "C" void kernel_launch(void* const* d_in, const int* in_sizes, int n_in,
                              void* d_out, int out_size, void* d_ws, size_t ws_size,
                              hipStream_t stream) {
  const float* x     = (const float*)d_in[0];
  const float* Wlx   = (const float*)d_in[1];
  const float* blx   = (const float*)d_in[2];
  const float* taus  = (const float*)d_in[5];
  const float* lsc   = (const float*)d_in[6];
  const float* Wro   = (const float*)d_in[7];
  const float* bro   = (const float*)d_in[8];
  const int*   eidx  = (const int*)d_in[9];
  int n = in_sizes[0] / 128;
  int e = in_sizes[9] / 2;
  const int* srcp = eidx;
  const int* dstp = eidx + e;
  float* out = (float*)d_out;

  char* ws = (char*)d_ws;
  size_t off = 0;
  auto alloc = [&](size_t bytes) -> void* {
    void* p = ws + off;
    off += (bytes + 255) & ~(size_t)255;
    return p;
  };
  int*      deg     = (int*)     alloc((size_t)n * 4);
  float*    dinv    = (float*)   alloc((size_t)n * 4);
  int*      rowptr  = (int*)     alloc((size_t)(n + 1) * 4);
  int*      cnt     = (int*)     alloc((size_t)n * 4);
  int*      bsum    = (int*)     alloc(1024 * 4);
  int*      csr_src = (int*)     alloc((size_t)e * 4);
  float*    csr_w   = (float*)   alloc((size_t)e * 4);
  float*    h       = (float*)   alloc((size_t)n * 128 * 4);
  float*    rhs     = (float*)   alloc((size_t)n * 128 * 4);
  unsigned* rhs_b   = (unsigned*)alloc((size_t)n * 64 * 4);
  unsigned* Z1b     = (unsigned*)alloc((size_t)n * 64 * 4);
  (void)ws_size; (void)n_in; (void)out_size;

  hipMemsetAsync(deg, 0, (size_t)n * 4, stream);
  hipMemsetAsync(cnt, 0, (size_t)n * 4, stream);

  int eb = (e + 255) / 256;
  int sb = (n + 1023) / 1024;
  k_deg<<<eb, 256, 0, stream>>>(dstp, deg, e);
  k_dinv<<<(n + 255) / 256, 256, 0, stream>>>(deg, dinv, n);
  k_scanA<<<sb, 1024, 0, stream>>>(deg, rowptr, bsum, n);
  k_scanB<<<1, 1024, 0, stream>>>(bsum, sb);
  k_scanC<<<sb, 1024, 0, stream>>>(rowptr, bsum, n, e);
  k_fill<<<eb, 256, 0, stream>>>(srcp, dstp, rowptr, cnt, dinv, csr_src, csr_w, e);

  int rb = (n + 15) / 16;
  k_gemm_in<<<rb, 256, 0, stream>>>(x, Wlx, blx, h, rhs, rhs_b, n);

  int ab = (n * 64 + 255) / 256;  // one wave per node
  for (int l = 0; l < 15; ++l) {
    k_agg <<<ab, 256, 0, stream>>>(rhs_b, rhs, Z1b, rowptr, csr_src, csr_w, n);
    k_agg2<<<ab, 256, 0, stream>>>(Z1b, rhs, rhs_b, h, rowptr, csr_src, csr_w, taus, l, n);
  }

  k_gemm_out<<<rb, 256, 0, stream>>>(h, Wro, bro, lsc, out, n);
}

// Round 4
// 2418.719 us; speedup vs baseline: 2.2686x; 1.0449x over previous
//
#include <hip/hip_runtime.h>

#define DT_C   0.1f
#define INV1P  0.9090909090909091f  /* 1/(1+DT) */

// ---------------- bf16 pack (RNE) ----------------

__device__ __forceinline__ unsigned bf16rne(float f) {
  unsigned b = __float_as_uint(f);
  return (b + 0x7fffu + ((b >> 16) & 1u)) >> 16;
}
__device__ __forceinline__ unsigned packbf(float x, float y) {
  return bf16rne(x) | (bf16rne(y) << 16);
}

// ---------------- setup: degree / dinv / scan / CSR fill ----------------

__global__ __launch_bounds__(256) void k_deg(const int* __restrict__ dst,
                                             int* __restrict__ deg, int e) {
  int i = blockIdx.x * 256 + threadIdx.x;
  if (i < e) atomicAdd(&deg[dst[i]], 1);
}

__global__ __launch_bounds__(256) void k_dinv(const int* __restrict__ deg,
                                              float* __restrict__ dinv, int n) {
  int i = blockIdx.x * 256 + threadIdx.x;
  if (i < n) {
    float d = (float)deg[i];
    dinv[i] = rsqrtf(fmaxf(d, 1.0f));
  }
}

// multi-block scan, phase A: per-block local exclusive scan + block sums
__global__ __launch_bounds__(1024) void k_scanA(const int* __restrict__ deg,
                                                int* __restrict__ rowptr,
                                                int* __restrict__ bsum, int n) {
  __shared__ int sm[1024];
  int t = threadIdx.x;
  int i = blockIdx.x * 1024 + t;
  int v = (i < n) ? deg[i] : 0;
  sm[t] = v;
  __syncthreads();
  for (int off = 1; off < 1024; off <<= 1) {
    int u = (t >= off) ? sm[t - off] : 0;
    __syncthreads();
    sm[t] += u;
    __syncthreads();
  }
  if (i < n) rowptr[i] = sm[t] - v;  // local exclusive
  if (t == 1023) bsum[blockIdx.x] = sm[t];
}

// phase B: single-block exclusive scan of block sums (G <= 1024)
__global__ __launch_bounds__(1024) void k_scanB(int* __restrict__ bsum, int g) {
  __shared__ int sm[1024];
  int t = threadIdx.x;
  int v = (t < g) ? bsum[t] : 0;
  sm[t] = v;
  __syncthreads();
  for (int off = 1; off < 1024; off <<= 1) {
    int u = (t >= off) ? sm[t - off] : 0;
    __syncthreads();
    sm[t] += u;
    __syncthreads();
  }
  if (t < g) bsum[t] = sm[t] - v;  // exclusive
}

// phase C: add block offsets; write rowptr[n]
__global__ __launch_bounds__(1024) void k_scanC(int* __restrict__ rowptr,
                                                const int* __restrict__ bsum,
                                                int n, int etot) {
  int i = blockIdx.x * 1024 + threadIdx.x;
  if (i < n) rowptr[i] += bsum[blockIdx.x];
  if (i == 0) rowptr[n] = etot;
}

// fill packed CSR {src, w}; deg doubles as countdown cursor (fills rows back-to-front)
__global__ __launch_bounds__(256) void k_fill(const int* __restrict__ src,
                                              const int* __restrict__ dst,
                                              const int* __restrict__ rowptr,
                                              int* __restrict__ deg,
                                              const float* __restrict__ dinv,
                                              int2* __restrict__ csr, int e) {
  int i = blockIdx.x * 256 + threadIdx.x;
  if (i >= e) return;
  int s = src[i], d = dst[i];
  int pos = rowptr[d] + atomicSub(&deg[d], 1) - 1;
  int2 sw;
  sw.x = s;
  sw.y = __float_as_int(dinv[s] * dinv[d]);
  csr[pos] = sw;
}

// ---------------- input GEMM: X0 = tanh(x @ Wlx + blx); init h, rhs, rhs_b ----------------

__global__ __launch_bounds__(256) void k_gemm_in(const float* __restrict__ x,
                                                 const float* __restrict__ Wlx,
                                                 const float* __restrict__ blx,
                                                 float* __restrict__ h,
                                                 float* __restrict__ rhs,
                                                 unsigned* __restrict__ rhs_b, int n) {
  __shared__ float ws[128 * 64];   // 32 KB
  __shared__ float xs[16 * 128];   // 8 KB
  int t = threadIdx.x;
  for (int i = t; i < 128 * 64; i += 256) ws[i] = Wlx[i];
  int base = blockIdx.x * 16;
  for (int v = t; v < 512; v += 256) {
    long idx = (long)base * 128 + v * 4;
    float4 val = {0.f, 0.f, 0.f, 0.f};
    if (idx < (long)n * 128) val = *(const float4*)(x + idx);
    *(float4*)(xs + v * 4) = val;
  }
  __syncthreads();
  int lane = t & 63;
  int wib  = t >> 6;
  float bl = blx[lane];
  for (int r = 0; r < 4; ++r) {
    int row = base + wib * 4 + r;
    if (row < n) {
      const float* xr = &xs[(wib * 4 + r) * 128];
      float acc = bl;
#pragma unroll 8
      for (int k = 0; k < 128; ++k) acc = fmaf(xr[k], ws[k * 64 + lane], acc);
      float X0 = tanhf(acc);
      int o = row * 128;
      h[o + lane]        = X0;
      h[o + 64 + lane]   = 1.0f;
      rhs[o + lane]      = X0;
      rhs[o + 64 + lane] = 1.0f + DT_C * (X0 - 1.0f);
      // bf16 copy of rhs, channel-pair layout: word w = channels (2w, 2w+1)
      float a = __shfl(X0, (2 * lane) & 63);
      float b = __shfl(X0, (2 * lane + 1) & 63);
      float px, py;
      if (lane < 32) { px = a; py = b; }
      else { px = 1.f + DT_C * (a - 1.f); py = 1.f + DT_C * (b - 1.f); }
      rhs_b[(size_t)row * 64 + lane] = packbf(px, py);
    }
  }
}

// ---------------- Jacobi step 1: Z1b = bf16((rhs_b + DT*agg(rhs_b)) / (1+DT)) ----------------
// one wave per node; lane holds channel pair {2*lane, 2*lane+1}; 16 gathers in flight.

__global__ __launch_bounds__(256) void k_agg(const unsigned* __restrict__ Zb,
                                             unsigned* __restrict__ Z1b,
                                             const int* __restrict__ rowptr,
                                             const int2* __restrict__ csr, int n) {
  int node = __builtin_amdgcn_readfirstlane((blockIdx.x * 256 + threadIdx.x) >> 6);
  if (node >= n) return;
  int lane = threadIdx.x & 63;
  int beg = __builtin_amdgcn_readfirstlane(rowptr[node]);
  int end = __builtin_amdgcn_readfirstlane(rowptr[node + 1]);
  unsigned rw = Zb[(size_t)node * 64 + lane];
  float rx = __uint_as_float(rw << 16);
  float ry = __uint_as_float(rw & 0xffff0000u);

  float accx[4] = {0.f, 0.f, 0.f, 0.f};
  float accy[4] = {0.f, 0.f, 0.f, 0.f};
  int last = end - 1;
  for (int e0 = beg; e0 < end; e0 += 16) {
    int2 sw[16]; float w[16]; unsigned u[16];
#pragma unroll
    for (int j = 0; j < 16; ++j) {
      int i  = e0 + j;
      int ic = (i < end) ? i : last;
      sw[j] = csr[ic];
      w[j]  = (i < end) ? __int_as_float(sw[j].y) : 0.f;
    }
#pragma unroll
    for (int j = 0; j < 16; ++j) u[j] = Zb[(size_t)sw[j].x * 64 + lane];
#pragma unroll
    for (int j = 0; j < 16; ++j) {
      float zx = __uint_as_float(u[j] << 16);
      float zy = __uint_as_float(u[j] & 0xffff0000u);
      accx[j & 3] = fmaf(w[j], zx, accx[j & 3]);
      accy[j & 3] = fmaf(w[j], zy, accy[j & 3]);
    }
  }
  float ax = (accx[0] + accx[1]) + (accx[2] + accx[3]);
  float ay = (accy[0] + accy[1]) + (accy[2] + accy[3]);
  float ox = (rx + DT_C * ax) * INV1P;
  float oy = (ry + DT_C * ay) * INV1P;
  Z1b[(size_t)node * 64 + lane] = packbf(ox, oy);
}

// ---------------- Jacobi step 2 fused with h-update and next-layer rhs ----------------

__global__ __launch_bounds__(256) void k_agg2(const unsigned* __restrict__ Z1b,
                                              float* __restrict__ rhs,
                                              unsigned* __restrict__ rhs_b,
                                              float* __restrict__ h,
                                              const int* __restrict__ rowptr,
                                              const int2* __restrict__ csr,
                                              const float* __restrict__ taus,
                                              int layer, int n) {
  int node = __builtin_amdgcn_readfirstlane((blockIdx.x * 256 + threadIdx.x) >> 6);
  if (node >= n) return;
  int lane = threadIdx.x & 63;
  int beg = __builtin_amdgcn_readfirstlane(rowptr[node]);
  int end = __builtin_amdgcn_readfirstlane(rowptr[node + 1]);
  float2 r  = ((const float2*)rhs)[(size_t)node * 64 + lane];
  float2 hv = ((const float2*)h)[(size_t)node * 64 + lane];

  float accx[4] = {0.f, 0.f, 0.f, 0.f};
  float accy[4] = {0.f, 0.f, 0.f, 0.f};
  int last = end - 1;
  for (int e0 = beg; e0 < end; e0 += 16) {
    int2 sw[16]; float w[16]; unsigned u[16];
#pragma unroll
    for (int j = 0; j < 16; ++j) {
      int i  = e0 + j;
      int ic = (i < end) ? i : last;
      sw[j] = csr[ic];
      w[j]  = (i < end) ? __int_as_float(sw[j].y) : 0.f;
    }
#pragma unroll
    for (int j = 0; j < 16; ++j) u[j] = Z1b[(size_t)sw[j].x * 64 + lane];
#pragma unroll
    for (int j = 0; j < 16; ++j) {
      float zx = __uint_as_float(u[j] << 16);
      float zy = __uint_as_float(u[j] & 0xffff0000u);
      accx[j & 3] = fmaf(w[j], zx, accx[j & 3]);
      accy[j & 3] = fmaf(w[j], zy, accy[j & 3]);
    }
  }
  float ax = (accx[0] + accx[1]) + (accx[2] + accx[3]);
  float ay = (accy[0] + accy[1]) + (accy[2] + accy[3]);

  float zx = (r.x + DT_C * ax) * INV1P;
  float zy = (r.y + DT_C * ay) * INV1P;
  float tv  = taus[layer];
  float tau = 1.0f / (1.0f + expf(-tv));
  float hx = (1.0f - tau) * hv.x + tau * zx;
  float hy = (1.0f - tau) * hv.y + tau * zy;
  float ox = __shfl_xor(hx, 32);
  float oy = __shfl_xor(hy, 32);
  float2 rn;
  if (lane < 32) {  // channels 2l,2l+1 are X; partner holds matching Y
    rn.x = hx + DT_C * hx * (1.0f - ox);
    rn.y = hy + DT_C * hy * (1.0f - oy);
  } else {          // Y channels; partner holds X
    rn.x = hx + DT_C * hx * (ox - 1.0f);
    rn.y = hy + DT_C * hy * (oy - 1.0f);
  }
  float2 hn = {hx, hy};
  ((float2*)h)[(size_t)node * 64 + lane]   = hn;
  ((float2*)rhs)[(size_t)node * 64 + lane] = rn;
  rhs_b[(size_t)node * 64 + lane] = packbf(rn.x, rn.y);
}

// ---------------- readout GEMM: out = logit_scale * X @ Wro + bro ----------------

__global__ __launch_bounds__(256) void k_gemm_out(const float* __restrict__ h,
                                                  const float* __restrict__ Wro,
                                                  const float* __restrict__ bro,
                                                  const float* __restrict__ lscale,
                                                  float* __restrict__ out, int n) {
  __shared__ float ws[64 * 40];
  __shared__ float xs[16 * 64];
  int t = threadIdx.x;
  for (int i = t; i < 64 * 40; i += 256) ws[i] = Wro[i];
  int base = blockIdx.x * 16;
  {
    int v = t;
    int rr = v >> 4;
    int row = base + rr;
    float4 val = {0.f, 0.f, 0.f, 0.f};
    if (row < n) val = *(const float4*)(h + (long)row * 128 + ((v * 4) & 63));
    *(float4*)(xs + v * 4) = val;
  }
  __syncthreads();
  float ls = *lscale;
  int lane = t & 63;
  int wib  = t >> 6;
  float bb = (lane < 40) ? bro[lane] : 0.f;
  for (int r = 0; r < 4; ++r) {
    int row = base + wib * 4 + r;
    if (row < n && lane < 40) {
      const float* xr = &xs[(wib * 4 + r) * 64];
      float acc = 0.f;
#pragma unroll
      for (int k = 0; k < 64; ++k) acc = fmaf(xr[k], ws[k * 40 + lane], acc);
      out[row * 40 + lane] = ls * acc + bb;
    }
  }
}

// ---------------- launch ----------------

extern "C" void kernel_launch(void* const* d_in, const int* in_sizes, int n_in,
                              void* d_out, int out_size, void* d_ws, size_t ws_size,
                              hipStream_t stream) {
  const float* x     = (const float*)d_in[0];
  const float* Wlx   = (const float*)d_in[1];
  const float* blx   = (const float*)d_in[2];
  const float* taus  = (const float*)d_in[5];
  const float* lsc   = (const float*)d_in[6];
  const float* Wro   = (const float*)d_in[7];
  const float* bro   = (const float*)d_in[8];
  const int*   eidx  = (const int*)d_in[9];
  int n = in_sizes[0] / 128;
  int e = in_sizes[9] / 2;
  const int* srcp = eidx;
  const int* dstp = eidx + e;
  float* out = (float*)d_out;

  char* ws = (char*)d_ws;
  size_t off = 0;
  auto alloc = [&](size_t bytes) -> void* {
    void* p = ws + off;
    off += (bytes + 255) & ~(size_t)255;
    return p;
  };
  int*      deg     = (int*)     alloc((size_t)n * 4);
  float*    dinv    = (float*)   alloc((size_t)n * 4);
  int*      rowptr  = (int*)     alloc((size_t)(n + 1) * 4);
  int*      bsum    = (int*)     alloc(1024 * 4);
  int2*     csr     = (int2*)    alloc((size_t)e * 8);
  float*    h       = (float*)   alloc((size_t)n * 128 * 4);
  float*    rhs     = (float*)   alloc((size_t)n * 128 * 4);
  unsigned* rhs_b   = (unsigned*)alloc((size_t)n * 64 * 4);
  unsigned* Z1b     = (unsigned*)alloc((size_t)n * 64 * 4);
  (void)ws_size; (void)n_in; (void)out_size;

  hipMemsetAsync(deg, 0, (size_t)n * 4, stream);

  int eb = (e + 255) / 256;
  int sb = (n + 1023) / 1024;
  k_deg<<<eb, 256, 0, stream>>>(dstp, deg, e);
  k_dinv<<<(n + 255) / 256, 256, 0, stream>>>(deg, dinv, n);
  k_scanA<<<sb, 1024, 0, stream>>>(deg, rowptr, bsum, n);
  k_scanB<<<1, 1024, 0, stream>>>(bsum, sb);
  k_scanC<<<sb, 1024, 0, stream>>>(rowptr, bsum, n, e);
  k_fill<<<eb, 256, 0, stream>>>(srcp, dstp, rowptr, deg, dinv, csr, e);

  int rb = (n + 15) / 16;
  k_gemm_in<<<rb, 256, 0, stream>>>(x, Wlx, blx, h, rhs, rhs_b, n);

  int ab = (n * 64 + 255) / 256;  // one wave per node
  for (int l = 0; l < 15; ++l) {
    k_agg <<<ab, 256, 0, stream>>>(rhs_b, Z1b, rowptr, csr, n);
    k_agg2<<<ab, 256, 0, stream>>>(Z1b, rhs, rhs_b, h, rowptr, csr, taus, l, n);
  }

  k_gemm_out<<<rb, 256, 0, stream>>>(h, Wro, bro, lsc, out, n);
}

// Round 5
// 2194.654 us; speedup vs baseline: 2.5002x; 1.1021x over previous
//
#include <hip/hip_runtime.h>

#define DT_C   0.1f
#define INV1P  0.9090909090909091f  /* 1/(1+DT) */

// ---------------- bf16 pack (RNE) ----------------

__device__ __forceinline__ unsigned bf16rne(float f) {
  unsigned b = __float_as_uint(f);
  return (b + 0x7fffu + ((b >> 16) & 1u)) >> 16;
}
__device__ __forceinline__ unsigned packbf(float x, float y) {
  return bf16rne(x) | (bf16rne(y) << 16);
}

// ---------------- setup: degree / dinv / scan / CSR fill ----------------

__global__ __launch_bounds__(256) void k_deg(const int* __restrict__ dst,
                                             int* __restrict__ deg, int e) {
  int i = blockIdx.x * 256 + threadIdx.x;
  if (i < e) atomicAdd(&deg[dst[i]], 1);
}

__global__ __launch_bounds__(256) void k_dinv(const int* __restrict__ deg,
                                              float* __restrict__ dinv, int n) {
  int i = blockIdx.x * 256 + threadIdx.x;
  if (i < n) {
    float d = (float)deg[i];
    dinv[i] = rsqrtf(fmaxf(d, 1.0f));
  }
}

// multi-block scan, phase A
__global__ __launch_bounds__(1024) void k_scanA(const int* __restrict__ deg,
                                                int* __restrict__ rowptr,
                                                int* __restrict__ bsum, int n) {
  __shared__ int sm[1024];
  int t = threadIdx.x;
  int i = blockIdx.x * 1024 + t;
  int v = (i < n) ? deg[i] : 0;
  sm[t] = v;
  __syncthreads();
  for (int off = 1; off < 1024; off <<= 1) {
    int u = (t >= off) ? sm[t - off] : 0;
    __syncthreads();
    sm[t] += u;
    __syncthreads();
  }
  if (i < n) rowptr[i] = sm[t] - v;
  if (t == 1023) bsum[blockIdx.x] = sm[t];
}

__global__ __launch_bounds__(1024) void k_scanB(int* __restrict__ bsum, int g) {
  __shared__ int sm[1024];
  int t = threadIdx.x;
  int v = (t < g) ? bsum[t] : 0;
  sm[t] = v;
  __syncthreads();
  for (int off = 1; off < 1024; off <<= 1) {
    int u = (t >= off) ? sm[t - off] : 0;
    __syncthreads();
    sm[t] += u;
    __syncthreads();
  }
  if (t < g) bsum[t] = sm[t] - v;
}

__global__ __launch_bounds__(1024) void k_scanC(int* __restrict__ rowptr,
                                                const int* __restrict__ bsum,
                                                int n, int etot) {
  int i = blockIdx.x * 1024 + threadIdx.x;
  if (i < n) rowptr[i] += bsum[blockIdx.x];
  if (i == 0) rowptr[n] = etot;
}

// fill packed CSR word: bits[16:0]=src (N<2^17), bits[31:17]=float bits of w (RNE)
__global__ __launch_bounds__(256) void k_fill(const int* __restrict__ src,
                                              const int* __restrict__ dst,
                                              const int* __restrict__ rowptr,
                                              int* __restrict__ deg,
                                              const float* __restrict__ dinv,
                                              unsigned* __restrict__ csr, int e) {
  int i = blockIdx.x * 256 + threadIdx.x;
  if (i >= e) return;
  int s = src[i], d = dst[i];
  int pos = rowptr[d] + atomicSub(&deg[d], 1) - 1;
  unsigned wb = __float_as_uint(dinv[s] * dinv[d]);
  wb = (wb + 0x10000u) & 0xFFFE0000u;   // round bits [16:0] away (w in (0,1], no overflow)
  csr[pos] = wb | (unsigned)s;
}

// ---------------- input GEMM: X0 = tanh(x @ Wlx + blx); init h, rhs_b ----------------

__global__ __launch_bounds__(256) void k_gemm_in(const float* __restrict__ x,
                                                 const float* __restrict__ Wlx,
                                                 const float* __restrict__ blx,
                                                 float* __restrict__ h,
                                                 unsigned* __restrict__ rhs_b, int n) {
  __shared__ float ws[128 * 64];   // 32 KB
  __shared__ float xs[16 * 128];   // 8 KB
  int t = threadIdx.x;
  for (int i = t; i < 128 * 64; i += 256) ws[i] = Wlx[i];
  int base = blockIdx.x * 16;
  for (int v = t; v < 512; v += 256) {
    long idx = (long)base * 128 + v * 4;
    float4 val = {0.f, 0.f, 0.f, 0.f};
    if (idx < (long)n * 128) val = *(const float4*)(x + idx);
    *(float4*)(xs + v * 4) = val;
  }
  __syncthreads();
  int lane = t & 63;
  int wib  = t >> 6;
  float bl = blx[lane];
  for (int r = 0; r < 4; ++r) {
    int row = base + wib * 4 + r;
    if (row < n) {
      const float* xr = &xs[(wib * 4 + r) * 128];
      float acc = bl;
#pragma unroll 8
      for (int k = 0; k < 128; ++k) acc = fmaf(xr[k], ws[k * 64 + lane], acc);
      float X0 = tanhf(acc);
      int o = row * 128;
      h[o + lane]        = X0;
      h[o + 64 + lane]   = 1.0f;
      // bf16 rhs, channel-pair layout: word w = channels (2w, 2w+1)
      float a = __shfl(X0, (2 * lane) & 63);
      float b = __shfl(X0, (2 * lane + 1) & 63);
      float px, py;
      if (lane < 32) { px = a; py = b; }
      else { px = 1.f + DT_C * (a - 1.f); py = 1.f + DT_C * (b - 1.f); }
      rhs_b[(size_t)row * 64 + lane] = packbf(px, py);
    }
  }
}

// ---------------- Jacobi step 1: Z1b = bf16((rhs_b + DT*agg(rhs_b)) / (1+DT)) ----------------

__global__ __launch_bounds__(256) void k_agg(const unsigned* __restrict__ Zb,
                                             unsigned* __restrict__ Z1b,
                                             const int* __restrict__ rowptr,
                                             const unsigned* __restrict__ csr, int n) {
  int node = __builtin_amdgcn_readfirstlane((blockIdx.x * 256 + threadIdx.x) >> 6);
  if (node >= n) return;
  int lane = threadIdx.x & 63;
  int beg = __builtin_amdgcn_readfirstlane(rowptr[node]);
  int end = __builtin_amdgcn_readfirstlane(rowptr[node + 1]);
  unsigned rw = Zb[(size_t)node * 64 + lane];
  float rx = __uint_as_float(rw << 16);
  float ry = __uint_as_float(rw & 0xffff0000u);

  float accx[4] = {0.f, 0.f, 0.f, 0.f};
  float accy[4] = {0.f, 0.f, 0.f, 0.f};
  int last = end - 1;
  for (int e0 = beg; e0 < end; e0 += 16) {
    unsigned c[16]; float w[16]; unsigned u[16];
#pragma unroll
    for (int j = 0; j < 16; ++j) {
      int i  = e0 + j;
      int ic = (i < end) ? i : last;
      c[j] = csr[ic];
      w[j] = (i < end) ? __uint_as_float(c[j] & 0xFFFE0000u) : 0.f;
    }
#pragma unroll
    for (int j = 0; j < 16; ++j) u[j] = Zb[(size_t)(c[j] & 0x1FFFFu) * 64 + lane];
#pragma unroll
    for (int j = 0; j < 16; ++j) {
      float zx = __uint_as_float(u[j] << 16);
      float zy = __uint_as_float(u[j] & 0xffff0000u);
      accx[j & 3] = fmaf(w[j], zx, accx[j & 3]);
      accy[j & 3] = fmaf(w[j], zy, accy[j & 3]);
    }
  }
  float ax = (accx[0] + accx[1]) + (accx[2] + accx[3]);
  float ay = (accy[0] + accy[1]) + (accy[2] + accy[3]);
  float ox = (rx + DT_C * ax) * INV1P;
  float oy = (ry + DT_C * ay) * INV1P;
  Z1b[(size_t)node * 64 + lane] = packbf(ox, oy);
}

// ---------------- Jacobi step 2 fused: recompute r from h, h-update, next rhs_b ----------------

__global__ __launch_bounds__(256) void k_agg2(const unsigned* __restrict__ Z1b,
                                              unsigned* __restrict__ rhs_b,
                                              float* __restrict__ h,
                                              const int* __restrict__ rowptr,
                                              const unsigned* __restrict__ csr,
                                              const float* __restrict__ taus,
                                              int layer, int n) {
  int node = __builtin_amdgcn_readfirstlane((blockIdx.x * 256 + threadIdx.x) >> 6);
  if (node >= n) return;
  int lane = threadIdx.x & 63;
  int beg = __builtin_amdgcn_readfirstlane(rowptr[node]);
  int end = __builtin_amdgcn_readfirstlane(rowptr[node + 1]);
  float2 hv = ((const float2*)h)[(size_t)node * 64 + lane];

  // recompute r = h + DT*f(h) in-register (identical math to the old stored rhs)
  float phx = __shfl_xor(hv.x, 32);
  float phy = __shfl_xor(hv.y, 32);
  float rx, ry;
  if (lane < 32) {  // X channels; partner holds matching Y
    rx = hv.x + DT_C * hv.x * (1.0f - phx);
    ry = hv.y + DT_C * hv.y * (1.0f - phy);
  } else {          // Y channels; partner holds X
    rx = hv.x + DT_C * hv.x * (phx - 1.0f);
    ry = hv.y + DT_C * hv.y * (phy - 1.0f);
  }

  float accx[4] = {0.f, 0.f, 0.f, 0.f};
  float accy[4] = {0.f, 0.f, 0.f, 0.f};
  int last = end - 1;
  for (int e0 = beg; e0 < end; e0 += 16) {
    unsigned c[16]; float w[16]; unsigned u[16];
#pragma unroll
    for (int j = 0; j < 16; ++j) {
      int i  = e0 + j;
      int ic = (i < end) ? i : last;
      c[j] = csr[ic];
      w[j] = (i < end) ? __uint_as_float(c[j] & 0xFFFE0000u) : 0.f;
    }
#pragma unroll
    for (int j = 0; j < 16; ++j) u[j] = Z1b[(size_t)(c[j] & 0x1FFFFu) * 64 + lane];
#pragma unroll
    for (int j = 0; j < 16; ++j) {
      float zx = __uint_as_float(u[j] << 16);
      float zy = __uint_as_float(u[j] & 0xffff0000u);
      accx[j & 3] = fmaf(w[j], zx, accx[j & 3]);
      accy[j & 3] = fmaf(w[j], zy, accy[j & 3]);
    }
  }
  float ax = (accx[0] + accx[1]) + (accx[2] + accx[3]);
  float ay = (accy[0] + accy[1]) + (accy[2] + accy[3]);

  float zx = (rx + DT_C * ax) * INV1P;
  float zy = (ry + DT_C * ay) * INV1P;
  float tv  = taus[layer];
  float tau = 1.0f / (1.0f + expf(-tv));
  float hx = (1.0f - tau) * hv.x + tau * zx;
  float hy = (1.0f - tau) * hv.y + tau * zy;
  float ox = __shfl_xor(hx, 32);
  float oy = __shfl_xor(hy, 32);
  float2 rn;
  if (lane < 32) {
    rn.x = hx + DT_C * hx * (1.0f - ox);
    rn.y = hy + DT_C * hy * (1.0f - oy);
  } else {
    rn.x = hx + DT_C * hx * (ox - 1.0f);
    rn.y = hy + DT_C * hy * (oy - 1.0f);
  }
  float2 hn = {hx, hy};
  ((float2*)h)[(size_t)node * 64 + lane] = hn;
  rhs_b[(size_t)node * 64 + lane] = packbf(rn.x, rn.y);
}

// ---------------- readout GEMM: out = logit_scale * X @ Wro + bro ----------------

__global__ __launch_bounds__(256) void k_gemm_out(const float* __restrict__ h,
                                                  const float* __restrict__ Wro,
                                                  const float* __restrict__ bro,
                                                  const float* __restrict__ lscale,
                                                  float* __restrict__ out, int n) {
  __shared__ float ws[64 * 40];
  __shared__ float xs[16 * 64];
  int t = threadIdx.x;
  for (int i = t; i < 64 * 40; i += 256) ws[i] = Wro[i];
  int base = blockIdx.x * 16;
  {
    int v = t;
    int rr = v >> 4;
    int row = base + rr;
    float4 val = {0.f, 0.f, 0.f, 0.f};
    if (row < n) val = *(const float4*)(h + (long)row * 128 + ((v * 4) & 63));
    *(float4*)(xs + v * 4) = val;
  }
  __syncthreads();
  float ls = *lscale;
  int lane = t & 63;
  int wib  = t >> 6;
  float bb = (lane < 40) ? bro[lane] : 0.f;
  for (int r = 0; r < 4; ++r) {
    int row = base + wib * 4 + r;
    if (row < n && lane < 40) {
      const float* xr = &xs[(wib * 4 + r) * 64];
      float acc = 0.f;
#pragma unroll
      for (int k = 0; k < 64; ++k) acc = fmaf(xr[k], ws[k * 40 + lane], acc);
      out[row * 40 + lane] = ls * acc + bb;
    }
  }
}

// ---------------- launch ----------------

extern "C" void kernel_launch(void* const* d_in, const int* in_sizes, int n_in,
                              void* d_out, int out_size, void* d_ws, size_t ws_size,
                              hipStream_t stream) {
  const float* x     = (const float*)d_in[0];
  const float* Wlx   = (const float*)d_in[1];
  const float* blx   = (const float*)d_in[2];
  const float* taus  = (const float*)d_in[5];
  const float* lsc   = (const float*)d_in[6];
  const float* Wro   = (const float*)d_in[7];
  const float* bro   = (const float*)d_in[8];
  const int*   eidx  = (const int*)d_in[9];
  int n = in_sizes[0] / 128;
  int e = in_sizes[9] / 2;
  const int* srcp = eidx;
  const int* dstp = eidx + e;
  float* out = (float*)d_out;

  char* ws = (char*)d_ws;
  size_t off = 0;
  auto alloc = [&](size_t bytes) -> void* {
    void* p = ws + off;
    off += (bytes + 255) & ~(size_t)255;
    return p;
  };
  int*      deg     = (int*)     alloc((size_t)n * 4);
  float*    dinv    = (float*)   alloc((size_t)n * 4);
  int*      rowptr  = (int*)     alloc((size_t)(n + 1) * 4);
  int*      bsum    = (int*)     alloc(1024 * 4);
  unsigned* csr     = (unsigned*)alloc((size_t)e * 4);
  float*    h       = (float*)   alloc((size_t)n * 128 * 4);
  unsigned* rhs_b   = (unsigned*)alloc((size_t)n * 64 * 4);
  unsigned* Z1b     = (unsigned*)alloc((size_t)n * 64 * 4);
  (void)ws_size; (void)n_in; (void)out_size;

  hipMemsetAsync(deg, 0, (size_t)n * 4, stream);

  int eb = (e + 255) / 256;
  int sb = (n + 1023) / 1024;
  k_deg<<<eb, 256, 0, stream>>>(dstp, deg, e);
  k_dinv<<<(n + 255) / 256, 256, 0, stream>>>(deg, dinv, n);
  k_scanA<<<sb, 1024, 0, stream>>>(deg, rowptr, bsum, n);
  k_scanB<<<1, 1024, 0, stream>>>(bsum, sb);
  k_scanC<<<sb, 1024, 0, stream>>>(rowptr, bsum, n, e);
  k_fill<<<eb, 256, 0, stream>>>(srcp, dstp, rowptr, deg, dinv, csr, e);

  int rb = (n + 15) / 16;
  k_gemm_in<<<rb, 256, 0, stream>>>(x, Wlx, blx, h, rhs_b, n);

  int ab = (n * 64 + 255) / 256;  // one wave per node
  for (int l = 0; l < 15; ++l) {
    k_agg <<<ab, 256, 0, stream>>>(rhs_b, Z1b, rowptr, csr, n);
    k_agg2<<<ab, 256, 0, stream>>>(Z1b, rhs_b, h, rowptr, csr, taus, l, n);
  }

  k_gemm_out<<<rb, 256, 0, stream>>>(h, Wro, bro, lsc, out, n);
}

// Round 6
// 2169.122 us; speedup vs baseline: 2.5296x; 1.0118x over previous
//
#include <hip/hip_runtime.h>

#define DT_C   0.1f
#define INV1P  0.9090909090909091f  /* 1/(1+DT) */

// ---------------- bf16 pack (RNE) ----------------

__device__ __forceinline__ unsigned bf16rne(float f) {
  unsigned b = __float_as_uint(f);
  return (b + 0x7fffu + ((b >> 16) & 1u)) >> 16;
}
__device__ __forceinline__ unsigned packbf(float x, float y) {
  return bf16rne(x) | (bf16rne(y) << 16);
}

// ---------------- setup: degree / dinv / scan / CSR fill ----------------

__global__ __launch_bounds__(256) void k_deg(const int* __restrict__ dst,
                                             int* __restrict__ deg, int e) {
  int i = blockIdx.x * 256 + threadIdx.x;
  if (i < e) atomicAdd(&deg[dst[i]], 1);
}

__global__ __launch_bounds__(256) void k_dinv(const int* __restrict__ deg,
                                              float* __restrict__ dinv, int n) {
  int i = blockIdx.x * 256 + threadIdx.x;
  if (i < n) {
    float d = (float)deg[i];
    dinv[i] = rsqrtf(fmaxf(d, 1.0f));
  }
}

__global__ __launch_bounds__(1024) void k_scanA(const int* __restrict__ deg,
                                                int* __restrict__ rowptr,
                                                int* __restrict__ bsum, int n) {
  __shared__ int sm[1024];
  int t = threadIdx.x;
  int i = blockIdx.x * 1024 + t;
  int v = (i < n) ? deg[i] : 0;
  sm[t] = v;
  __syncthreads();
  for (int off = 1; off < 1024; off <<= 1) {
    int u = (t >= off) ? sm[t - off] : 0;
    __syncthreads();
    sm[t] += u;
    __syncthreads();
  }
  if (i < n) rowptr[i] = sm[t] - v;
  if (t == 1023) bsum[blockIdx.x] = sm[t];
}

__global__ __launch_bounds__(1024) void k_scanB(int* __restrict__ bsum, int g) {
  __shared__ int sm[1024];
  int t = threadIdx.x;
  int v = (t < g) ? bsum[t] : 0;
  sm[t] = v;
  __syncthreads();
  for (int off = 1; off < 1024; off <<= 1) {
    int u = (t >= off) ? sm[t - off] : 0;
    __syncthreads();
    sm[t] += u;
    __syncthreads();
  }
  if (t < g) bsum[t] = sm[t] - v;
}

__global__ __launch_bounds__(1024) void k_scanC(int* __restrict__ rowptr,
                                                const int* __restrict__ bsum,
                                                int n, int etot) {
  int i = blockIdx.x * 1024 + threadIdx.x;
  if (i < n) rowptr[i] += bsum[blockIdx.x];
  if (i == 0) rowptr[n] = etot;
}

// packed CSR word: bits[16:0]=src (N<2^17), bits[31:17]=float bits of w (RNE)
__global__ __launch_bounds__(256) void k_fill(const int* __restrict__ src,
                                              const int* __restrict__ dst,
                                              const int* __restrict__ rowptr,
                                              int* __restrict__ deg,
                                              const float* __restrict__ dinv,
                                              unsigned* __restrict__ csr, int e) {
  int i = blockIdx.x * 256 + threadIdx.x;
  if (i >= e) return;
  int s = src[i], d = dst[i];
  int pos = rowptr[d] + atomicSub(&deg[d], 1) - 1;
  unsigned wb = __float_as_uint(dinv[s] * dinv[d]);
  wb = (wb + 0x10000u) & 0xFFFE0000u;
  csr[pos] = wb | (unsigned)s;
}

// ---------------- input GEMM: W in registers, x staged in LDS ----------------
// lane = output column; wreg[k] = Wlx[k][lane]. Grid-stride over 16-row tiles.

__global__ __launch_bounds__(256) void k_gemm_in(const float* __restrict__ x,
                                                 const float* __restrict__ Wlx,
                                                 const float* __restrict__ blx,
                                                 float* __restrict__ h,
                                                 unsigned* __restrict__ rhs_b,
                                                 int n, int ntiles) {
  __shared__ float xs[16 * 128];   // 8 KB
  int t = threadIdx.x;
  int lane = t & 63;
  int wib  = t >> 6;
  float wreg[128];
#pragma unroll
  for (int k = 0; k < 128; ++k) wreg[k] = Wlx[k * 64 + lane];
  float bl = blx[lane];

  for (int tile = blockIdx.x; tile < ntiles; tile += gridDim.x) {
    int base = tile * 16;
    __syncthreads();
    for (int v = t; v < 512; v += 256) {
      long idx = (long)base * 128 + v * 4;
      float4 val = {0.f, 0.f, 0.f, 0.f};
      if (idx < (long)n * 128) val = *(const float4*)(x + idx);
      *(float4*)(xs + v * 4) = val;
    }
    __syncthreads();
    for (int r = 0; r < 4; ++r) {
      int row = base + wib * 4 + r;
      if (row < n) {
        const float* xr = &xs[(wib * 4 + r) * 128];
        float acc = bl;
#pragma unroll
        for (int kq = 0; kq < 32; ++kq) {
          float4 xv = *(const float4*)(xr + kq * 4);
          acc = fmaf(xv.x, wreg[4 * kq],     acc);
          acc = fmaf(xv.y, wreg[4 * kq + 1], acc);
          acc = fmaf(xv.z, wreg[4 * kq + 2], acc);
          acc = fmaf(xv.w, wreg[4 * kq + 3], acc);
        }
        float X0 = tanhf(acc);
        int o = row * 128;
        h[o + lane]      = X0;
        h[o + 64 + lane] = 1.0f;
        float a = __shfl(X0, (2 * lane) & 63);
        float b = __shfl(X0, (2 * lane + 1) & 63);
        float px, py;
        if (lane < 32) { px = a; py = b; }
        else { px = 1.f + DT_C * (a - 1.f); py = 1.f + DT_C * (b - 1.f); }
        rhs_b[(size_t)row * 64 + lane] = packbf(px, py);
      }
    }
  }
}

// ---------------- Jacobi step 1 ----------------
// lane = (g = lane>>4 edge subgroup, q = lane&15 word quartet).
// One dwordx4 gather fetches 4 full 256B rows (one per subgroup).

__global__ __launch_bounds__(256) void k_agg(const unsigned* __restrict__ Zb,
                                             unsigned* __restrict__ Z1b,
                                             const int* __restrict__ rowptr,
                                             const unsigned* __restrict__ csr, int n) {
  int node = __builtin_amdgcn_readfirstlane((blockIdx.x * 256 + threadIdx.x) >> 6);
  if (node >= n) return;
  int lane = threadIdx.x & 63;
  int g = lane >> 4, q = lane & 15;
  int beg = __builtin_amdgcn_readfirstlane(rowptr[node]);
  int end = __builtin_amdgcn_readfirstlane(rowptr[node + 1]);
  uint4 rr = *((const uint4*)(Zb + (size_t)node * 64) + q);

  float accx[4] = {0.f, 0.f, 0.f, 0.f};
  float accy[4] = {0.f, 0.f, 0.f, 0.f};
  int last = end - 1;
  for (int e0 = beg; e0 < end; e0 += 16) {
    unsigned c[4]; float wk[4]; uint4 u[4];
#pragma unroll
    for (int k = 0; k < 4; ++k) {
      int idx = e0 + 4 * k + g;
      int ic  = (idx < end) ? idx : last;
      c[k]  = csr[ic];
      wk[k] = (idx < end) ? __uint_as_float(c[k] & 0xFFFE0000u) : 0.f;
    }
#pragma unroll
    for (int k = 0; k < 4; ++k)
      u[k] = *((const uint4*)(Zb + (size_t)(c[k] & 0x1FFFFu) * 64) + q);
#pragma unroll
    for (int k = 0; k < 4; ++k) {
      unsigned uw[4] = {u[k].x, u[k].y, u[k].z, u[k].w};
#pragma unroll
      for (int i = 0; i < 4; ++i) {
        float zx = __uint_as_float(uw[i] << 16);
        float zy = __uint_as_float(uw[i] & 0xffff0000u);
        accx[i] = fmaf(wk[k], zx, accx[i]);
        accy[i] = fmaf(wk[k], zy, accy[i]);
      }
    }
  }
#pragma unroll
  for (int i = 0; i < 4; ++i) {
    accx[i] += __shfl_xor(accx[i], 16);
    accx[i] += __shfl_xor(accx[i], 32);
    accy[i] += __shfl_xor(accy[i], 16);
    accy[i] += __shfl_xor(accy[i], 32);
  }
  unsigned rw[4] = {rr.x, rr.y, rr.z, rr.w};
  unsigned ow[4];
#pragma unroll
  for (int i = 0; i < 4; ++i) {
    float rx = __uint_as_float(rw[i] << 16);
    float ry = __uint_as_float(rw[i] & 0xffff0000u);
    ow[i] = packbf((rx + DT_C * accx[i]) * INV1P,
                   (ry + DT_C * accy[i]) * INV1P);
  }
  if (g == 0) {
    uint4 o; o.x = ow[0]; o.y = ow[1]; o.z = ow[2]; o.w = ow[3];
    *((uint4*)(Z1b + (size_t)node * 64) + q) = o;
  }
}

// ---------------- Jacobi step 2 fused: r from h, h-update, next rhs_b ----------------
// quartet q holds words 4q..4q+3 = channels 8q..8q+7; X/Y partner = shfl_xor(8).

__global__ __launch_bounds__(256) void k_agg2(const unsigned* __restrict__ Z1b,
                                              unsigned* __restrict__ rhs_b,
                                              float* __restrict__ h,
                                              const int* __restrict__ rowptr,
                                              const unsigned* __restrict__ csr,
                                              const float* __restrict__ taus,
                                              int layer, int n) {
  int node = __builtin_amdgcn_readfirstlane((blockIdx.x * 256 + threadIdx.x) >> 6);
  if (node >= n) return;
  int lane = threadIdx.x & 63;
  int g = lane >> 4, q = lane & 15;
  int beg = __builtin_amdgcn_readfirstlane(rowptr[node]);
  int end = __builtin_amdgcn_readfirstlane(rowptr[node + 1]);

  float4 h0 = ((const float4*)(h + (size_t)node * 128))[2 * q];
  float4 h1 = ((const float4*)(h + (size_t)node * 128))[2 * q + 1];
  float hv[8] = {h0.x, h0.y, h0.z, h0.w, h1.x, h1.y, h1.z, h1.w};
  float pv[8];
#pragma unroll
  for (int i = 0; i < 8; ++i) pv[i] = __shfl_xor(hv[i], 8);
  bool isX = (q < 8);
  float rch[8];
#pragma unroll
  for (int i = 0; i < 8; ++i)
    rch[i] = isX ? hv[i] + DT_C * hv[i] * (1.0f - pv[i])
                 : hv[i] + DT_C * hv[i] * (pv[i] - 1.0f);

  float accx[4] = {0.f, 0.f, 0.f, 0.f};
  float accy[4] = {0.f, 0.f, 0.f, 0.f};
  int last = end - 1;
  for (int e0 = beg; e0 < end; e0 += 16) {
    unsigned c[4]; float wk[4]; uint4 u[4];
#pragma unroll
    for (int k = 0; k < 4; ++k) {
      int idx = e0 + 4 * k + g;
      int ic  = (idx < end) ? idx : last;
      c[k]  = csr[ic];
      wk[k] = (idx < end) ? __uint_as_float(c[k] & 0xFFFE0000u) : 0.f;
    }
#pragma unroll
    for (int k = 0; k < 4; ++k)
      u[k] = *((const uint4*)(Z1b + (size_t)(c[k] & 0x1FFFFu) * 64) + q);
#pragma unroll
    for (int k = 0; k < 4; ++k) {
      unsigned uw[4] = {u[k].x, u[k].y, u[k].z, u[k].w};
#pragma unroll
      for (int i = 0; i < 4; ++i) {
        float zx = __uint_as_float(uw[i] << 16);
        float zy = __uint_as_float(uw[i] & 0xffff0000u);
        accx[i] = fmaf(wk[k], zx, accx[i]);
        accy[i] = fmaf(wk[k], zy, accy[i]);
      }
    }
  }
#pragma unroll
  for (int i = 0; i < 4; ++i) {
    accx[i] += __shfl_xor(accx[i], 16);
    accx[i] += __shfl_xor(accx[i], 32);
    accy[i] += __shfl_xor(accy[i], 16);
    accy[i] += __shfl_xor(accy[i], 32);
  }

  float tv  = taus[layer];
  float tau = 1.0f / (1.0f + expf(-tv));
  float hnew[8];
#pragma unroll
  for (int i = 0; i < 4; ++i) {
    float zx = (rch[2 * i]     + DT_C * accx[i]) * INV1P;
    float zy = (rch[2 * i + 1] + DT_C * accy[i]) * INV1P;
    hnew[2 * i]     = (1.0f - tau) * hv[2 * i]     + tau * zx;
    hnew[2 * i + 1] = (1.0f - tau) * hv[2 * i + 1] + tau * zy;
  }
  if (g == 0) {
    float4 o0 = {hnew[0], hnew[1], hnew[2], hnew[3]};
    float4 o1 = {hnew[4], hnew[5], hnew[6], hnew[7]};
    ((float4*)(h + (size_t)node * 128))[2 * q]     = o0;
    ((float4*)(h + (size_t)node * 128))[2 * q + 1] = o1;
  }
  float pn[8];
#pragma unroll
  for (int i = 0; i < 8; ++i) pn[i] = __shfl_xor(hnew[i], 8);
  unsigned ow[4];
#pragma unroll
  for (int i = 0; i < 4; ++i) {
    float ra = isX ? hnew[2 * i] + DT_C * hnew[2 * i] * (1.0f - pn[2 * i])
                   : hnew[2 * i] + DT_C * hnew[2 * i] * (pn[2 * i] - 1.0f);
    float rb = isX ? hnew[2 * i + 1] + DT_C * hnew[2 * i + 1] * (1.0f - pn[2 * i + 1])
                   : hnew[2 * i + 1] + DT_C * hnew[2 * i + 1] * (pn[2 * i + 1] - 1.0f);
    ow[i] = packbf(ra, rb);
  }
  if (g == 0) {
    uint4 o; o.x = ow[0]; o.y = ow[1]; o.z = ow[2]; o.w = ow[3];
    *((uint4*)(rhs_b + (size_t)node * 64) + q) = o;
  }
}

// ---------------- readout GEMM ----------------

__global__ __launch_bounds__(256) void k_gemm_out(const float* __restrict__ h,
                                                  const float* __restrict__ Wro,
                                                  const float* __restrict__ bro,
                                                  const float* __restrict__ lscale,
                                                  float* __restrict__ out, int n) {
  __shared__ float ws[64 * 40];
  __shared__ float xs[16 * 64];
  int t = threadIdx.x;
  for (int i = t; i < 64 * 40; i += 256) ws[i] = Wro[i];
  int base = blockIdx.x * 16;
  {
    int v = t;
    int rr = v >> 4;
    int row = base + rr;
    float4 val = {0.f, 0.f, 0.f, 0.f};
    if (row < n) val = *(const float4*)(h + (long)row * 128 + ((v * 4) & 63));
    *(float4*)(xs + v * 4) = val;
  }
  __syncthreads();
  float ls = *lscale;
  int lane = t & 63;
  int wib  = t >> 6;
  float bb = (lane < 40) ? bro[lane] : 0.f;
  for (int r = 0; r < 4; ++r) {
    int row = base + wib * 4 + r;
    if (row < n && lane < 40) {
      const float* xr = &xs[(wib * 4 + r) * 64];
      float acc = 0.f;
#pragma unroll
      for (int k = 0; k < 64; ++k) acc = fmaf(xr[k], ws[k * 40 + lane], acc);
      out[row * 40 + lane] = ls * acc + bb;
    }
  }
}

// ---------------- launch ----------------

extern "C" void kernel_launch(void* const* d_in, const int* in_sizes, int n_in,
                              void* d_out, int out_size, void* d_ws, size_t ws_size,
                              hipStream_t stream) {
  const float* x     = (const float*)d_in[0];
  const float* Wlx   = (const float*)d_in[1];
  const float* blx   = (const float*)d_in[2];
  const float* taus  = (const float*)d_in[5];
  const float* lsc   = (const float*)d_in[6];
  const float* Wro   = (const float*)d_in[7];
  const float* bro   = (const float*)d_in[8];
  const int*   eidx  = (const int*)d_in[9];
  int n = in_sizes[0] / 128;
  int e = in_sizes[9] / 2;
  const int* srcp = eidx;
  const int* dstp = eidx + e;
  float* out = (float*)d_out;

  char* ws = (char*)d_ws;
  size_t off = 0;
  auto alloc = [&](size_t bytes) -> void* {
    void* p = ws + off;
    off += (bytes + 255) & ~(size_t)255;
    return p;
  };
  int*      deg     = (int*)     alloc((size_t)n * 4);
  float*    dinv    = (float*)   alloc((size_t)n * 4);
  int*      rowptr  = (int*)     alloc((size_t)(n + 1) * 4);
  int*      bsum    = (int*)     alloc(1024 * 4);
  unsigned* csr     = (unsigned*)alloc((size_t)e * 4);
  float*    h       = (float*)   alloc((size_t)n * 128 * 4);
  unsigned* rhs_b   = (unsigned*)alloc((size_t)n * 64 * 4);
  unsigned* Z1b     = (unsigned*)alloc((size_t)n * 64 * 4);
  (void)ws_size; (void)n_in; (void)out_size;

  hipMemsetAsync(deg, 0, (size_t)n * 4, stream);

  int eb = (e + 255) / 256;
  int sb = (n + 1023) / 1024;
  k_deg<<<eb, 256, 0, stream>>>(dstp, deg, e);
  k_dinv<<<(n + 255) / 256, 256, 0, stream>>>(deg, dinv, n);
  k_scanA<<<sb, 1024, 0, stream>>>(deg, rowptr, bsum, n);
  k_scanB<<<1, 1024, 0, stream>>>(bsum, sb);
  k_scanC<<<sb, 1024, 0, stream>>>(rowptr, bsum, n, e);
  k_fill<<<eb, 256, 0, stream>>>(srcp, dstp, rowptr, deg, dinv, csr, e);

  int ntiles = (n + 15) / 16;
  int gb = ntiles < 1024 ? ntiles : 1024;
  k_gemm_in<<<gb, 256, 0, stream>>>(x, Wlx, blx, h, rhs_b, n, ntiles);

  int ab = (n * 64 + 255) / 256;  // one wave per node
  for (int l = 0; l < 15; ++l) {
    k_agg <<<ab, 256, 0, stream>>>(rhs_b, Z1b, rowptr, csr, n);
    k_agg2<<<ab, 256, 0, stream>>>(Z1b, rhs_b, h, rowptr, csr, taus, l, n);
  }

  k_gemm_out<<<(n + 15) / 16, 256, 0, stream>>>(h, Wro, bro, lsc, out, n);
}